// Round 10
// baseline (171.930 us; speedup 1.0000x reference)
//
#include <hip/hip_runtime.h>
#include <hip/hip_bf16.h>

#define NB   64
#define NREG 4
#define ND   768
#define NH   37
#define NW   37
#define NC   5                      // 1 + NREG cues
#define NP   (NH * NW)              // 1369
#define BPB  16                     // sim blocks per batch -> 1024 blocks
#define PPB  ((NP + BPB - 1) / BPB) // 86 patches per block
#define NWAVE 4
#define DEPTH 2                     // LDS slots per wave (private double buffer)
#define SIM_BLOCKS (NB * BPB)
#define ROI_BLOCKS (NB * NC)

// Map float -> unsigned int preserving order (total order, -inf .. +inf)
__device__ __forceinline__ unsigned int ord_of(float f) {
    unsigned int u = __float_as_uint(f);
    return (u & 0x80000000u) ? ~u : (u | 0x80000000u);
}

// DPP-based wave64 sum: 6 full-rate VALU steps, no LDS ops, no lgkm waits.
// Result is the full 64-lane sum in LANE 63 (other lanes hold partials).
template <int CTRL>
__device__ __forceinline__ float dpp_add_step(float x) {
    int y = __builtin_amdgcn_update_dpp(0, __float_as_int(x), CTRL, 0xf, 0xf, true);
    return x + __int_as_float(y);
}
__device__ __forceinline__ float wave_sum_lane63(float x) {
    x = dpp_add_step<0x111>(x);  // row_shr:1
    x = dpp_add_step<0x112>(x);  // row_shr:2
    x = dpp_add_step<0x114>(x);  // row_shr:4
    x = dpp_add_step<0x118>(x);  // row_shr:8
    x = dpp_add_step<0x142>(x);  // row_bcast:15
    x = dpp_add_step<0x143>(x);  // row_bcast:31
    return x;                    // lane 63 = total
}

// Issue 3x global_load_lds (1 KB each) for one patch into one wave-slot.
__device__ __forceinline__ void stage_patch(const float* __restrict__ gbase,
                                            float* lslot, int lane) {
    const float* g = gbase + lane * 4;
    #pragma unroll
    for (int k = 0; k < 3; ++k) {
        __builtin_amdgcn_global_load_lds(
            (const __attribute__((address_space(1))) void*)(g + k * 256),
            (__attribute__((address_space(3))) void*)(lslot + k * 256),
            16, 0, 0);
    }
}

__global__ __launch_bounds__(256, 4) void fused_encoder_kernel(
    const float* __restrict__ cls_tok,
    const float* __restrict__ regs,
    const float* __restrict__ patches,
    const int* __restrict__ roi_side_p,
    float* __restrict__ out,
    unsigned long long* __restrict__ pkeys,
    unsigned int* __restrict__ cnt)
{
    const int tid  = threadIdx.x;
    const int wave = tid >> 6;
    const int lane = tid & 63;

    __shared__ float lds[DEPTH][NWAVE][ND];        // sim staging, 24 KB
    __shared__ unsigned long long lk[NWAVE][NC];   // sim per-wave keys
    __shared__ unsigned long long skey;            // roi final key
    __shared__ float red_x[3], red_y[3];           // roi norm partials

    if (blockIdx.x < SIM_BLOCKS) {
        // ================= SIM PATH (identical structure to R9) =============
        const int b  = blockIdx.x / BPB;
        const int pb = blockIdx.x % BPB;

        float4 cue[NC][3];
        #pragma unroll
        for (int c = 0; c < NC; ++c) {
            const float* cb = (c == 0) ? (cls_tok + (size_t)b * ND)
                                       : (regs + ((size_t)b * NREG + (c - 1)) * ND);
            #pragma unroll
            for (int k = 0; k < 3; ++k)
                cue[c][k] = *reinterpret_cast<const float4*>(cb + k * 256 + lane * 4);
        }

        float best[NC];
        int   bidx[NC];
        #pragma unroll
        for (int c = 0; c < NC; ++c) { best[c] = -3.4e38f; bidx[c] = 0; }

        const int pstart = pb * PPB;
        const int p1     = min(NP, pstart + PPB);
        const size_t bb  = (size_t)b * NP;
        const int p0     = pstart + wave;   // wave-uniform

        #pragma unroll
        for (int s = 0; s < DEPTH; ++s) {
            const int pp = p0 + s * NWAVE;
            if (pp < p1) stage_patch(patches + (bb + pp) * ND, &lds[s][wave][0], lane);
        }

        int it = 0;
        for (int pp = p0; pp < p1; pp += NWAVE, ++it) {
            const int s = it & 1;
            const bool more = (pp + NWAVE) < p1;  // wave-uniform

            if (more) asm volatile("s_waitcnt vmcnt(3)" ::: "memory");
            else      asm volatile("s_waitcnt vmcnt(0)" ::: "memory");

            const float* l = &lds[s][wave][0] + lane * 4;
            const float4 v0 = *reinterpret_cast<const float4*>(l);
            const float4 v1 = *reinterpret_cast<const float4*>(l + 256);
            const float4 v2 = *reinterpret_cast<const float4*>(l + 512);

            asm volatile("s_waitcnt lgkmcnt(0)" ::: "memory");

            const int pf = pp + DEPTH * NWAVE;
            if (pf < p1) stage_patch(patches + (bb + pf) * ND, &lds[s][wave][0], lane);

            float sacc[NC];
            #pragma unroll
            for (int c = 0; c < NC; ++c) {
                sacc[c] = v0.x * cue[c][0].x + v0.y * cue[c][0].y
                        + v0.z * cue[c][0].z + v0.w * cue[c][0].w
                        + v1.x * cue[c][1].x + v1.y * cue[c][1].y
                        + v1.z * cue[c][1].z + v1.w * cue[c][1].w
                        + v2.x * cue[c][2].x + v2.y * cue[c][2].y
                        + v2.z * cue[c][2].z + v2.w * cue[c][2].w;
            }
            #pragma unroll
            for (int c = 0; c < NC; ++c) {
                const float t = wave_sum_lane63(sacc[c]);
                if (t > best[c]) { best[c] = t; bidx[c] = pp; }
            }
        }

        if (lane == 63) {  // DPP sum lives in lane 63
            #pragma unroll
            for (int c = 0; c < NC; ++c) {
                lk[wave][c] =
                    ((unsigned long long)ord_of(best[c]) << 32) |
                    (unsigned long long)(unsigned)(NP - 1 - bidx[c]);
            }
        }
        __syncthreads();
        if (tid < NC) {
            unsigned long long k = lk[0][tid];
            k = max(k, lk[1][tid]);
            k = max(k, lk[2][tid]);
            k = max(k, lk[3][tid]);
            // device-scope publish (coherent point)
            atomicExch(&pkeys[(b * NC + tid) * BPB + pb], k);
        }
        __syncthreads();
        if (tid == 0) {
            __threadfence();
            atomicAdd(&cnt[b], 1u);   // cnt memset to 0 each call
        }
    } else {
        // ================= ROI PATH =========================================
        const int rb = blockIdx.x - SIM_BLOCKS;
        const int b  = rb / NC;
        const int c  = rb % NC;

        if (tid == 0) {
            while (atomicAdd(&cnt[b], 0u) < BPB) __builtin_amdgcn_s_sleep(2);
        }
        __syncthreads();
        __threadfence();  // acquire

        // Wave 0, lanes 0..15: atomic-read the 16 partial keys, reduce max.
        if (wave == 0) {
            unsigned long long k = (lane < BPB)
                ? atomicAdd(&pkeys[(b * NC + c) * BPB + lane], 0ull) : 0ull;
            #pragma unroll
            for (int off = 8; off > 0; off >>= 1) {
                const unsigned long long o = __shfl_xor(k, off, 64);
                k = max(k, o);
            }
            if (lane == 0) skey = k;
        }
        __syncthreads();
        const unsigned long long key = skey;

        const int r = roi_side_p[0] >> 1;
        const int idx = NP - 1 - (int)(key & 0xFFFFFFFFu);
        const int hh = idx / NW, ww = idx % NW;
        const int h0 = max(0, hh - r), h1 = min(NH - 1, hh + r);
        const int w0 = max(0, ww - r), w1 = min(NW - 1, ww + r);
        const float inv_cnt = 1.0f / (float)((h1 - h0 + 1) * (w1 - w0 + 1));
        const size_t bb = (size_t)b * NP;

        if (tid < 192) {   // 192 threads x float4 = 768 dims; wave 3 idles
            float4 acc = make_float4(0.f, 0.f, 0.f, 0.f);
            if (r == 2) {
                #pragma unroll
                for (int dh = -2; dh <= 2; ++dh) {
                    #pragma unroll
                    for (int dw = -2; dw <= 2; ++dw) {
                        const int h = hh + dh, w = ww + dw;
                        const bool ok = ((unsigned)h < NH) && ((unsigned)w < NW);
                        const int pidx = ok ? (h * NW + w) : idx;
                        const float m = ok ? 1.0f : 0.0f;
                        const float4 v = *reinterpret_cast<const float4*>(
                            patches + (bb + pidx) * ND + tid * 4);
                        acc.x += v.x * m; acc.y += v.y * m;
                        acc.z += v.z * m; acc.w += v.w * m;
                    }
                }
            } else {
                for (int h = h0; h <= h1; ++h)
                    for (int w = w0; w <= w1; ++w) {
                        const float4 v = *reinterpret_cast<const float4*>(
                            patches + (bb + h * NW + w) * ND + tid * 4);
                        acc.x += v.x; acc.y += v.y; acc.z += v.z; acc.w += v.w;
                    }
            }
            acc.x *= inv_cnt; acc.y *= inv_cnt; acc.z *= inv_cnt; acc.w *= inv_cnt;

            const float* cb = (c == 0) ? (cls_tok + (size_t)b * ND)
                                       : (regs + ((size_t)b * NREG + (c - 1)) * ND);
            const float4 v = *reinterpret_cast<const float4*>(cb + tid * 4);

            float sx = v.x * v.x + v.y * v.y + v.z * v.z + v.w * v.w;
            float sy = acc.x * acc.x + acc.y * acc.y + acc.z * acc.z + acc.w * acc.w;
            #pragma unroll
            for (int off = 32; off > 0; off >>= 1) {
                sx += __shfl_xor(sx, off, 64);
                sy += __shfl_xor(sy, off, 64);
            }
            if (lane == 0) { red_x[wave] = sx; red_y[wave] = sy; }
        }
        __syncthreads();
        if (tid < 192) {
            const float tot_x = red_x[0] + red_x[1] + red_x[2];
            const float tot_y = red_y[0] + red_y[1] + red_y[2];
            const float inv_nc = 1.0f / fmaxf(sqrtf(tot_x), 1e-12f);
            const float inv_nr = 1.0f / fmaxf(sqrtf(tot_y), 1e-12f);

            const float* cb = (c == 0) ? (cls_tok + (size_t)b * ND)
                                       : (regs + ((size_t)b * NREG + (c - 1)) * ND);
            const float4 v = *reinterpret_cast<const float4*>(cb + tid * 4);
            // recompute acc-scaled values cheaply? acc lives in regs above only
            // within the previous if-block; recompute path below re-reads it.
            // Instead keep acc alive: duplicated block structure avoided by
            // storing normalized outputs here directly via fresh accumulate:
            float4 acc = make_float4(0.f, 0.f, 0.f, 0.f);
            if (r == 2) {
                #pragma unroll
                for (int dh = -2; dh <= 2; ++dh) {
                    #pragma unroll
                    for (int dw = -2; dw <= 2; ++dw) {
                        const int h = hh + dh, w = ww + dw;
                        const bool ok = ((unsigned)h < NH) && ((unsigned)w < NW);
                        const int pidx = ok ? (h * NW + w) : idx;
                        const float m = ok ? 1.0f : 0.0f;
                        const float4 t = *reinterpret_cast<const float4*>(
                            patches + (bb + pidx) * ND + tid * 4);
                        acc.x += t.x * m; acc.y += t.y * m;
                        acc.z += t.z * m; acc.w += t.w * m;
                    }
                }
            } else {
                for (int h = h0; h <= h1; ++h)
                    for (int w = w0; w <= w1; ++w) {
                        const float4 t = *reinterpret_cast<const float4*>(
                            patches + (bb + h * NW + w) * ND + tid * 4);
                        acc.x += t.x; acc.y += t.y; acc.z += t.z; acc.w += t.w;
                    }
            }
            acc.x *= inv_cnt; acc.y *= inv_cnt; acc.z *= inv_cnt; acc.w *= inv_cnt;

            float4* oc = reinterpret_cast<float4*>(out + ((size_t)b * 2 * NC + c) * ND) + tid;
            float4* om = reinterpret_cast<float4*>(out + ((size_t)b * 2 * NC + NC + c) * ND) + tid;
            *oc = make_float4(v.x * inv_nc, v.y * inv_nc, v.z * inv_nc, v.w * inv_nc);
            *om = make_float4(acc.x * inv_nr, acc.y * inv_nr, acc.z * inv_nr, acc.w * inv_nr);
        }
    }
}

extern "C" void kernel_launch(void* const* d_in, const int* in_sizes, int n_in,
                              void* d_out, int out_size, void* d_ws, size_t ws_size,
                              hipStream_t stream) {
    const float* cls_tok = (const float*)d_in[0];
    const float* regs    = (const float*)d_in[1];
    const float* patches = (const float*)d_in[2];
    const int*   roi     = (const int*)d_in[3];
    float* out = (float*)d_out;

    unsigned long long* pkeys = (unsigned long long*)d_ws;
    unsigned int* cnt = (unsigned int*)((char*)d_ws +
                         (size_t)NB * NC * BPB * sizeof(unsigned long long));

    // Known counter start each call (ws is poisoned once, never restored).
    hipMemsetAsync(cnt, 0, NB * sizeof(unsigned int), stream);

    fused_encoder_kernel<<<SIM_BLOCKS + ROI_BLOCKS, 256, 0, stream>>>(
        cls_tok, regs, patches, roi, out, pkeys, cnt);
}

// Round 11
// 53.121 us; speedup vs baseline: 3.2366x; 3.2366x over previous
//
#include <hip/hip_runtime.h>
#include <hip/hip_bf16.h>

#define NB   64
#define NREG 4
#define ND   768
#define NH   37
#define NW   37
#define NC   5                      // 1 + NREG cues
#define NP   (NH * NW)              // 1369
#define BPB  16                     // blocks per batch -> 1024 blocks = 4/CU
#define PPB  ((NP + BPB - 1) / BPB) // 86 patches per block
#define NWAVE 4
#define DEPTH 2                     // LDS slots per wave (private double buffer)

// Map float -> unsigned int preserving order (total order, -inf .. +inf)
__device__ __forceinline__ unsigned int ord_of(float f) {
    unsigned int u = __float_as_uint(f);
    return (u & 0x80000000u) ? ~u : (u | 0x80000000u);
}

// DPP-based wave64 sum: 6 full-rate VALU steps, no LDS ops, no lgkm waits.
// Result is the full 64-lane sum in LANE 63 (other lanes hold partials).
template <int CTRL>
__device__ __forceinline__ float dpp_add_step(float x) {
    int y = __builtin_amdgcn_update_dpp(0, __float_as_int(x), CTRL, 0xf, 0xf, true);
    return x + __int_as_float(y);
}
__device__ __forceinline__ float wave_sum_lane63(float x) {
    x = dpp_add_step<0x111>(x);  // row_shr:1
    x = dpp_add_step<0x112>(x);  // row_shr:2
    x = dpp_add_step<0x114>(x);  // row_shr:4
    x = dpp_add_step<0x118>(x);  // row_shr:8
    x = dpp_add_step<0x142>(x);  // row_bcast:15
    x = dpp_add_step<0x143>(x);  // row_bcast:31
    return x;                    // lane 63 = total
}

// Issue 3x global_load_lds (1 KB each) for one patch into one wave-slot.
__device__ __forceinline__ void stage_patch(const float* __restrict__ gbase,
                                            float* lslot, int lane) {
    const float* g = gbase + lane * 4;
    #pragma unroll
    for (int k = 0; k < 3; ++k) {
        __builtin_amdgcn_global_load_lds(
            (const __attribute__((address_space(1))) void*)(g + k * 256),
            (__attribute__((address_space(3))) void*)(lslot + k * 256),
            16, 0, 0);
    }
}

__global__ __launch_bounds__(256, 4) void sim_argmax_kernel(
    const float* __restrict__ cls_tok,
    const float* __restrict__ regs,
    const float* __restrict__ patches,
    unsigned long long* __restrict__ pkeys)
{
    const int b    = blockIdx.x / BPB;
    const int pb   = blockIdx.x % BPB;
    const int wave = threadIdx.x >> 6;
    const int lane = threadIdx.x & 63;

    // Per-wave private staging buffers: 2 slots x 3 KB. No barriers needed.
    __shared__ float lds[DEPTH][NWAVE][ND];   // 24 KB

    // Preload this lane's slice of all 5 cues into registers (15 float4).
    float4 cue[NC][3];
    #pragma unroll
    for (int c = 0; c < NC; ++c) {
        const float* cb = (c == 0) ? (cls_tok + (size_t)b * ND)
                                   : (regs + ((size_t)b * NREG + (c - 1)) * ND);
        #pragma unroll
        for (int k = 0; k < 3; ++k)
            cue[c][k] = *reinterpret_cast<const float4*>(cb + k * 256 + lane * 4);
    }

    float best[NC];
    int   bidx[NC];
    #pragma unroll
    for (int c = 0; c < NC; ++c) { best[c] = -3.4e38f; bidx[c] = 0; }

    const int pstart = pb * PPB;
    const int p1     = min(NP, pstart + PPB);
    const size_t bb  = (size_t)b * NP;
    const int p0     = pstart + wave;   // wave-uniform

    // Prologue: fill both slots.
    #pragma unroll
    for (int s = 0; s < DEPTH; ++s) {
        const int pp = p0 + s * NWAVE;
        if (pp < p1) stage_patch(patches + (bb + pp) * ND, &lds[s][wave][0], lane);
    }

    int it = 0;
    for (int pp = p0; pp < p1; pp += NWAVE, ++it) {
        const int s = it & 1;
        const bool more = (pp + NWAVE) < p1;  // wave-uniform

        // Counted wait: current slot's 3 loads done; next slot's 3 stay in flight.
        if (more) asm volatile("s_waitcnt vmcnt(3)" ::: "memory");
        else      asm volatile("s_waitcnt vmcnt(0)" ::: "memory");

        const float* l = &lds[s][wave][0] + lane * 4;
        const float4 v0 = *reinterpret_cast<const float4*>(l);
        const float4 v1 = *reinterpret_cast<const float4*>(l + 256);
        const float4 v2 = *reinterpret_cast<const float4*>(l + 512);

        // Ensure the ds_reads complete before re-staging overwrites the slot.
        asm volatile("s_waitcnt lgkmcnt(0)" ::: "memory");

        // Prefetch this slot <- patch pp + 8 (issues while we compute).
        const int pf = pp + DEPTH * NWAVE;
        if (pf < p1) stage_patch(patches + (bb + pf) * ND, &lds[s][wave][0], lane);

        float sacc[NC];
        #pragma unroll
        for (int c = 0; c < NC; ++c) {
            sacc[c] = v0.x * cue[c][0].x + v0.y * cue[c][0].y
                    + v0.z * cue[c][0].z + v0.w * cue[c][0].w
                    + v1.x * cue[c][1].x + v1.y * cue[c][1].y
                    + v1.z * cue[c][1].z + v1.w * cue[c][1].w
                    + v2.x * cue[c][2].x + v2.y * cue[c][2].y
                    + v2.z * cue[c][2].z + v2.w * cue[c][2].w;
        }
        #pragma unroll
        for (int c = 0; c < NC; ++c) {
            const float t = wave_sum_lane63(sacc[c]);
            if (t > best[c]) { best[c] = t; bidx[c] = pp; }
        }
    }

    // Combine the 4 waves' bests in LDS, then one plain store per cue.
    __shared__ unsigned long long lk[NWAVE][NC];
    if (lane == 63) {  // DPP sum lives in lane 63
        #pragma unroll
        for (int c = 0; c < NC; ++c) {
            lk[wave][c] =
                ((unsigned long long)ord_of(best[c]) << 32) |
                (unsigned long long)(unsigned)(NP - 1 - bidx[c]);  // low idx wins ties
        }
    }
    __syncthreads();
    if (threadIdx.x < NC) {
        unsigned long long k = lk[0][threadIdx.x];
        k = max(k, lk[1][threadIdx.x]);
        k = max(k, lk[2][threadIdx.x]);
        k = max(k, lk[3][threadIdx.x]);
        pkeys[(b * NC + threadIdx.x) * BPB + pb] = k;
    }
}

// One block (192 threads) per (b, cue): reduce partial keys, clipped-window
// mean (branchless unrolled 5x5 for r==2, full MLP), normalize both tokens.
__global__ __launch_bounds__(192) void roi_norm_kernel(
    const float* __restrict__ cls_tok,
    const float* __restrict__ regs,
    const float* __restrict__ patches,
    const unsigned long long* __restrict__ pkeys,
    const int* __restrict__ roi_side_p,
    float* __restrict__ out)
{
    const int b   = blockIdx.x / NC;
    const int c   = blockIdx.x % NC;
    const int tid = threadIdx.x;          // 0..191, tid*4 covers 768 dims
    const int wave = tid >> 6, lane = tid & 63;
    const int r = roi_side_p[0] >> 1;

    // All threads redundantly reduce the BPB partial keys (uniform loads).
    const unsigned long long* pk = pkeys + (b * NC + c) * BPB;
    unsigned long long key = pk[0];
    #pragma unroll
    for (int i = 1; i < BPB; ++i) key = max(key, pk[i]);

    const int idx = NP - 1 - (int)(key & 0xFFFFFFFFu);
    const int hh = idx / NW, ww = idx % NW;
    const int h0 = max(0, hh - r), h1 = min(NH - 1, hh + r);
    const int w0 = max(0, ww - r), w1 = min(NW - 1, ww + r);
    const float inv_cnt = 1.0f / (float)((h1 - h0 + 1) * (w1 - w0 + 1));

    const size_t bb = (size_t)b * NP;
    float4 acc = make_float4(0.f, 0.f, 0.f, 0.f);

    if (r == 2) {
        // Branchless 5x5: 25 unconditional float4 loads, mask-FMA accumulate.
        #pragma unroll
        for (int dh = -2; dh <= 2; ++dh) {
            #pragma unroll
            for (int dw = -2; dw <= 2; ++dw) {
                const int h = hh + dh, w = ww + dw;
                const bool ok = ((unsigned)h < NH) && ((unsigned)w < NW);
                const int pidx = ok ? (h * NW + w) : idx;  // safe fallback addr
                const float m = ok ? 1.0f : 0.0f;
                const float4 v = *reinterpret_cast<const float4*>(
                    patches + (bb + pidx) * ND + tid * 4);
                acc.x += v.x * m; acc.y += v.y * m;
                acc.z += v.z * m; acc.w += v.w * m;
            }
        }
    } else {
        for (int h = h0; h <= h1; ++h) {
            for (int w = w0; w <= w1; ++w) {
                const float4 v = *reinterpret_cast<const float4*>(
                    patches + (bb + h * NW + w) * ND + tid * 4);
                acc.x += v.x; acc.y += v.y; acc.z += v.z; acc.w += v.w;
            }
        }
    }
    acc.x *= inv_cnt; acc.y *= inv_cnt; acc.z *= inv_cnt; acc.w *= inv_cnt;

    const float* cb = (c == 0) ? (cls_tok + (size_t)b * ND)
                               : (regs + ((size_t)b * NREG + (c - 1)) * ND);
    const float4 v = *reinterpret_cast<const float4*>(cb + tid * 4);

    // Block-reduce two sums of squares (cue, roi) across 3 waves.
    float sx = v.x * v.x + v.y * v.y + v.z * v.z + v.w * v.w;
    float sy = acc.x * acc.x + acc.y * acc.y + acc.z * acc.z + acc.w * acc.w;
    #pragma unroll
    for (int off = 32; off > 0; off >>= 1) {
        sx += __shfl_xor(sx, off, 64);
        sy += __shfl_xor(sy, off, 64);
    }
    __shared__ float red_x[3], red_y[3];
    if (lane == 0) { red_x[wave] = sx; red_y[wave] = sy; }
    __syncthreads();
    const float tot_x = red_x[0] + red_x[1] + red_x[2];
    const float tot_y = red_y[0] + red_y[1] + red_y[2];
    const float inv_nc = 1.0f / fmaxf(sqrtf(tot_x), 1e-12f);
    const float inv_nr = 1.0f / fmaxf(sqrtf(tot_y), 1e-12f);

    float4* oc = reinterpret_cast<float4*>(out + ((size_t)b * 2 * NC + c) * ND) + tid;
    float4* om = reinterpret_cast<float4*>(out + ((size_t)b * 2 * NC + NC + c) * ND) + tid;
    *oc = make_float4(v.x * inv_nc, v.y * inv_nc, v.z * inv_nc, v.w * inv_nc);
    *om = make_float4(acc.x * inv_nr, acc.y * inv_nr, acc.z * inv_nr, acc.w * inv_nr);
}

extern "C" void kernel_launch(void* const* d_in, const int* in_sizes, int n_in,
                              void* d_out, int out_size, void* d_ws, size_t ws_size,
                              hipStream_t stream) {
    const float* cls_tok = (const float*)d_in[0];
    const float* regs    = (const float*)d_in[1];
    const float* patches = (const float*)d_in[2];
    const int*   roi     = (const int*)d_in[3];
    float* out = (float*)d_out;
    unsigned long long* pkeys = (unsigned long long*)d_ws;

    sim_argmax_kernel<<<NB * BPB, 256, 0, stream>>>(cls_tok, regs, patches, pkeys);
    roi_norm_kernel<<<NB * NC, 192, 0, stream>>>(cls_tok, regs, patches, pkeys, roi, out);
}